// Round 5
// baseline (304.196 us; speedup 1.0000x reference)
//
#include <hip/hip_runtime.h>
#include <math.h>

#define N 4096
#define D 512
#define TOPK 10
#define TOPK_HALF 5
#define NT 32                      // N/128 tiles per dim
#define TRI_BLOCKS (NT * (NT + 1) / 2)   // 528
#define WC_BLOCKS (N * TOPK_HALF / 4)    // 5120, one wave per task

typedef __bf16 bf16;
typedef __bf16 bf16x8 __attribute__((ext_vector_type(8)));
typedef float f32x4 __attribute__((ext_vector_type(4)));
typedef unsigned long long u64;

__device__ __forceinline__ void gl_lds16(const void* g, void* l) {
  __builtin_amdgcn_global_load_lds(
      (const __attribute__((address_space(1))) void*)g,
      (__attribute__((address_space(3))) void*)l, 16, 0, 0);
}

// ---------------- zero rowsum ----------------
__global__ void k_zero(float* rowsum) {
  int i = blockIdx.x * 256 + threadIdx.x;
  if (i < N) rowsum[i] = 0.f;
}

// ---------------- K0: L2-normalize -> bf16 rows + rsq of bf16 values ----------------
__global__ __launch_bounds__(256) void k_normalize(const float* __restrict__ x,
                                                   bf16* __restrict__ y,
                                                   float* __restrict__ rowsq) {
  int row = blockIdx.x, tid = threadIdx.x;
  const float* xr = x + (size_t)row * D;
  float v0 = xr[tid], v1 = xr[tid + 256];
  float ss = v0 * v0 + v1 * v1;
  __shared__ float red[4];
  for (int off = 32; off > 0; off >>= 1) ss += __shfl_down(ss, off, 64);
  if ((tid & 63) == 0) red[tid >> 6] = ss;
  __syncthreads();
  float tot = red[0] + red[1] + red[2] + red[3];
  float inv = 1.0f / fmaxf(sqrtf(tot), 1e-12f);
  bf16 b0 = (bf16)(v0 * inv), b1 = (bf16)(v1 * inv);
  bf16* yr = y + (size_t)row * D;
  yr[tid] = b0; yr[tid + 256] = b1;
  float f0 = (float)b0, f1 = (float)b1;
  float s2 = f0 * f0 + f1 * f1;
  for (int off = 32; off > 0; off >>= 1) s2 += __shfl_down(s2, off, 64);
  __syncthreads();
  if ((tid & 63) == 0) red[tid >> 6] = s2;
  __syncthreads();
  if (tid == 0) rowsq[row] = red[0] + red[1] + red[2] + red[3];
}

// ---------------- Pass 1: symmetric S-gram -> rowsum only (no G store) ----------------
__global__ __launch_bounds__(256) void k_sgram_rowsum(const bf16* __restrict__ Y,
                                                      const float* __restrict__ rsq,
                                                      float* __restrict__ rowsum) {
  __shared__ bf16 As[128 * 32];
  __shared__ bf16 Bs[128 * 32];
  // triangular map: blockIdx -> (by, bx) with by <= bx
  int t = blockIdx.x, by = 0;
  while (t >= NT - by) { t -= NT - by; ++by; }
  int bx = by + t;

  int tid = threadIdx.x;
  int lane = tid & 63, w = tid >> 6;
  int wr = w >> 1, wc = w & 1;
  f32x4 acc[4][4] = {};

  const char* Abase = (const char*)(Y + (size_t)(by * 128) * D);
  const char* Bbase = (const char*)(Y + (size_t)(bx * 128) * D);
  int c0 = tid, c1 = tid + 256;
  int r0 = c0 >> 2, q0 = c0 & 3;
  int r1 = c1 >> 2, q1 = c1 & 3;
  bf16* lA0 = As + (size_t)(w * 64) * 8;
  bf16* lA1 = As + (size_t)(256 + w * 64) * 8;
  bf16* lB0 = Bs + (size_t)(w * 64) * 8;
  bf16* lB1 = Bs + (size_t)(256 + w * 64) * 8;

  int arow = wr * 64 + (lane & 15);
  int brow = wc * 64 + (lane & 15);
  int kq = (lane >> 4) * 8;

  for (int k0 = 0; k0 < D; k0 += 32) {
    size_t off0 = (size_t)r0 * (D * 2) + (size_t)k0 * 2 + q0 * 16;
    size_t off1 = (size_t)r1 * (D * 2) + (size_t)k0 * 2 + q1 * 16;
    gl_lds16(Abase + off0, lA0);
    gl_lds16(Abase + off1, lA1);
    gl_lds16(Bbase + off0, lB0);
    gl_lds16(Bbase + off1, lB1);
    __syncthreads();
    bf16x8 af[4], bfr[4];
#pragma unroll
    for (int u = 0; u < 4; ++u) af[u] = *(bf16x8*)&As[(arow + u * 16) * 32 + kq];
#pragma unroll
    for (int v = 0; v < 4; ++v) bfr[v] = *(bf16x8*)&Bs[(brow + v * 16) * 32 + kq];
#pragma unroll
    for (int u = 0; u < 4; ++u)
#pragma unroll
      for (int v = 0; v < 4; ++v)
        acc[u][v] = __builtin_amdgcn_mfma_f32_16x16x32_bf16(af[u], bfr[v], acc[u][v], 0, 0, 0);
    __syncthreads();
  }

  int colb = bx * 128 + wc * 64 + (lane & 15);
  int rowb = by * 128 + wr * 64 + ((lane >> 4) << 2);
  float rsc[4];
#pragma unroll
  for (int v = 0; v < 4; ++v) rsc[v] = rsq[colb + v * 16];
  float cpart[4] = {0.f, 0.f, 0.f, 0.f};
#pragma unroll
  for (int u = 0; u < 4; ++u) {
    float rsr[4];
#pragma unroll
    for (int reg = 0; reg < 4; ++reg) rsr[reg] = rsq[rowb + u * 16 + reg];
    float rpart[4] = {0.f, 0.f, 0.f, 0.f};
#pragma unroll
    for (int v = 0; v < 4; ++v) {
      f32x4 a = acc[u][v];
#pragma unroll
      for (int reg = 0; reg < 4; ++reg) {
        float sq = fmaxf(rsr[reg] + rsc[v] - 2.0f * a[reg], 0.0f);
        float val = sqrtf(sq);
        rpart[reg] += val;
        cpart[v] += val;
      }
    }
#pragma unroll
    for (int reg = 0; reg < 4; ++reg) {
      float s = rpart[reg];
      s += __shfl_xor(s, 1, 64);
      s += __shfl_xor(s, 2, 64);
      s += __shfl_xor(s, 4, 64);
      s += __shfl_xor(s, 8, 64);
      if ((lane & 15) == 0) atomicAdd(&rowsum[rowb + u * 16 + reg], s);
    }
  }
  if (bx > by) {
#pragma unroll
    for (int v = 0; v < 4; ++v) {
      float s = cpart[v];
      s += __shfl_xor(s, 16, 64);
      s += __shfl_xor(s, 32, 64);
      if (lane < 16) atomicAdd(&rowsum[bx * 128 + wc * 64 + v * 16 + lane], s);
    }
  }
}

// ---------------- K2: mean = rowsum / N ----------------
__global__ void k_mean(const float* __restrict__ rowsum, float* __restrict__ mean) {
  int i = blockIdx.x * 256 + threadIdx.x;
  if (i < N) mean[i] = rowsum[i] * (1.0f / (float)N);
}

// ---------------- Pass 2: fused dual gram -> dense partial + per-tile topk cands ----------------
__global__ __launch_bounds__(256) void k_fused(const bf16* __restrict__ S,
                                               const bf16* __restrict__ T,
                                               const float* __restrict__ rsq_s,
                                               const float* __restrict__ rsq_t,
                                               const float* __restrict__ mean,
                                               const int* __restrict__ ids,
                                               u64* __restrict__ cand,
                                               double* __restrict__ pd) {
  // union: K-loop staging (As 8K | Bs 8K) overlapped with epilogue wpT (33K)
  __shared__ __align__(16) char smemu[128 * 65 * 4];      // 33.3 KB
  __shared__ __align__(16) _Float16 sdT[128 * 130];       // 33.3 KB (padded)
  __shared__ int idsRow[128], idsCol[128];
  __shared__ double dred[4];
  bf16* As = (bf16*)smemu;
  bf16* Bs = (bf16*)(smemu + 8192);
  float* wpT = (float*)smemu;

  int bx = blockIdx.x, by = blockIdx.y;
  int tid = threadIdx.x;
  int lane = tid & 63, w = tid >> 6;
  int wr = w >> 1, wc = w & 1;

  if (tid < 128) idsRow[tid] = ids[by * 128 + tid];
  else idsCol[tid - 128] = ids[bx * 128 + (tid - 128)];

  int c0 = tid, c1 = tid + 256;
  int r0 = c0 >> 2, q0 = c0 & 3;
  int r1 = c1 >> 2, q1 = c1 & 3;
  bf16* lA0 = As + (size_t)(w * 64) * 8;
  bf16* lA1 = As + (size_t)(256 + w * 64) * 8;
  bf16* lB0 = Bs + (size_t)(w * 64) * 8;
  bf16* lB1 = Bs + (size_t)(256 + w * 64) * 8;
  int arow = wr * 64 + (lane & 15);
  int brow = wc * 64 + (lane & 15);
  int kq = (lane >> 4) * 8;
  int rowLb = wr * 64 + ((lane >> 4) << 2);   // local row base for this lane
  int colL16 = lane & 15;                      // local col within 16-tile

  f32x4 acc[4][4] = {};
  // ---- S K-loop ----
  {
    const char* Abase = (const char*)(S + (size_t)(by * 128) * D);
    const char* Bbase = (const char*)(S + (size_t)(bx * 128) * D);
    for (int k0 = 0; k0 < D; k0 += 32) {
      size_t off0 = (size_t)r0 * (D * 2) + (size_t)k0 * 2 + q0 * 16;
      size_t off1 = (size_t)r1 * (D * 2) + (size_t)k0 * 2 + q1 * 16;
      gl_lds16(Abase + off0, lA0);
      gl_lds16(Abase + off1, lA1);
      gl_lds16(Bbase + off0, lB0);
      gl_lds16(Bbase + off1, lB1);
      __syncthreads();
      bf16x8 af[4], bfr[4];
#pragma unroll
      for (int u = 0; u < 4; ++u) af[u] = *(bf16x8*)&As[(arow + u * 16) * 32 + kq];
#pragma unroll
      for (int v = 0; v < 4; ++v) bfr[v] = *(bf16x8*)&Bs[(brow + v * 16) * 32 + kq];
#pragma unroll
      for (int u = 0; u < 4; ++u)
#pragma unroll
        for (int v = 0; v < 4; ++v)
          acc[u][v] = __builtin_amdgcn_mfma_f32_16x16x32_bf16(af[u], bfr[v], acc[u][v], 0, 0, 0);
      __syncthreads();
    }
  }
  // write sd (f16) to padded LDS tile
#pragma unroll
  for (int u = 0; u < 4; ++u)
#pragma unroll
    for (int v = 0; v < 4; ++v) {
      f32x4 a = acc[u][v];
#pragma unroll
      for (int reg = 0; reg < 4; ++reg) {
        int rl = rowLb + u * 16 + reg;
        int cl = wc * 64 + v * 16 + colL16;
        float sq = fmaxf(rsq_s[by * 128 + rl] + rsq_s[bx * 128 + cl] - 2.0f * a[reg], 0.0f);
        sdT[rl * 130 + cl] = (_Float16)sqrtf(sq);
      }
    }
  // ---- T K-loop (reuse As/Bs; acc reset) ----
#pragma unroll
  for (int u = 0; u < 4; ++u)
#pragma unroll
    for (int v = 0; v < 4; ++v) acc[u][v] = (f32x4){0.f, 0.f, 0.f, 0.f};
  {
    const char* Abase = (const char*)(T + (size_t)(by * 128) * D);
    const char* Bbase = (const char*)(T + (size_t)(bx * 128) * D);
    for (int k0 = 0; k0 < D; k0 += 32) {
      size_t off0 = (size_t)r0 * (D * 2) + (size_t)k0 * 2 + q0 * 16;
      size_t off1 = (size_t)r1 * (D * 2) + (size_t)k0 * 2 + q1 * 16;
      gl_lds16(Abase + off0, lA0);
      gl_lds16(Abase + off1, lA1);
      gl_lds16(Bbase + off0, lB0);
      gl_lds16(Bbase + off1, lB1);
      __syncthreads();
      bf16x8 af[4], bfr[4];
#pragma unroll
      for (int u = 0; u < 4; ++u) af[u] = *(bf16x8*)&As[(arow + u * 16) * 32 + kq];
#pragma unroll
      for (int v = 0; v < 4; ++v) bfr[v] = *(bf16x8*)&Bs[(brow + v * 16) * 32 + kq];
#pragma unroll
      for (int u = 0; u < 4; ++u)
#pragma unroll
        for (int v = 0; v < 4; ++v)
          acc[u][v] = __builtin_amdgcn_mfma_f32_16x16x32_bf16(af[u], bfr[v], acc[u][v], 0, 0, 0);
      __syncthreads();
    }
  }

  // ---- epilogue: two 64-col chunks; stage wp, scan for dense + topk ----
  int sr_ = tid & 127, sh = tid >> 7;        // scan: row sr_, col-half sh
  float invm = 1.0f / mean[by * 128 + sr_];
  int idi = idsRow[sr_];
  int gi_scan = by * 128 + sr_;
  u64 top[TOPK];
#pragma unroll
  for (int o = 0; o < TOPK; ++o) top[o] = 0ULL;
  float dsumf = 0.f;

  for (int c = 0; c < 2; ++c) {
    if (wc == c) {
      // this wave's cols live in chunk c: write wp = exp(-tsq)
#pragma unroll
      for (int u = 0; u < 4; ++u)
#pragma unroll
        for (int v = 0; v < 4; ++v) {
          f32x4 a = acc[u][v];
#pragma unroll
          for (int reg = 0; reg < 4; ++reg) {
            int rl = rowLb + u * 16 + reg;
            int cl = v * 16 + colL16;          // within chunk (0..63)
            float tsq = fmaxf(rsq_t[by * 128 + rl] +
                              rsq_t[bx * 128 + c * 64 + cl] - 2.0f * a[reg], 0.0f);
            wpT[rl * 65 + cl] = expf(-tsq);
          }
        }
    }
    __syncthreads();
    // scan 32 cols of this chunk
#pragma unroll 4
    for (int k = 0; k < 32; ++k) {
      int cl = sh * 32 + k;                    // within chunk
      int ccl = c * 64 + cl;                   // within tile
      float wp = wpT[sr_ * 65 + cl];
      float sd = (float)sdT[sr_ * 130 + ccl];
      int gj = bx * 128 + ccl;
      if (gj != gi_scan) {
        float sdn = sd * invm;
        float r = fmaxf(1.0f - sdn, 0.0f); r *= r;
        dsumf += r + 0.5f * wp * (sdn * sdn - r);
      }
      float wkey = (idsCol[ccl] == idi) ? 1.0f : wp;
      u64 key = ((u64)__float_as_uint(wkey) << 32) |
                (u64)(0xFFFFFFFFu - (unsigned)gj);
      if (key > top[TOPK - 1]) {
        top[TOPK - 1] = key;
#pragma unroll
        for (int a = TOPK - 2; a >= 0; --a) {
          if (top[a + 1] > top[a]) { u64 tt = top[a]; top[a] = top[a + 1]; top[a + 1] = tt; }
        }
      }
    }
    __syncthreads();
  }

  // dense partial reduction
  double dl = (double)dsumf;
  for (int off = 32; off > 0; off >>= 1) dl += __shfl_down(dl, off, 64);
  if ((tid & 63) == 0) dred[tid >> 6] = dl;

  // per-row merge of the two scan threads' lists (reuse sdT as u64 buffer)
  u64* lists = (u64*)sdT;
  __syncthreads();          // sdT reads done; dred written
#pragma unroll
  for (int o = 0; o < TOPK; ++o) lists[tid * TOPK + o] = top[o];
  __syncthreads();
  if (tid < 128) {
    u64 out[TOPK];
    int pa = 0, pb = 0;
#pragma unroll
    for (int o = 0; o < TOPK; ++o) {
      u64 ka = lists[tid * TOPK + pa];
      u64 kb = lists[(tid + 128) * TOPK + pb];
      bool ta = ka >= kb;
      out[o] = ta ? ka : kb;
      pa += ta ? 1 : 0;
      pb += ta ? 0 : 1;
    }
    u64* dst = cand + ((size_t)(by * 128 + tid) * NT + bx) * TOPK;
#pragma unroll
    for (int o = 0; o < TOPK; ++o) dst[o] = out[o];
  }
  if (tid == 0) pd[by * NT + bx] = dred[0] + dred[1] + dred[2] + dred[3];
}

// ---------------- K merge: exact global top-10 from 32 per-tile lists ----------------
__global__ __launch_bounds__(256) void k_merge(const u64* __restrict__ cand,
                                               int* __restrict__ topk) {
  __shared__ u64 lists[256 * TOPK];
  int tid = threadIdx.x;
  int t = blockIdx.x * 256 + tid;
  int row = t >> 2, q = t & 3;
  const u64* src = cand + (size_t)row * (NT * TOPK) + q * (NT * TOPK / 4);
  u64 top[TOPK];
#pragma unroll
  for (int o = 0; o < TOPK; ++o) top[o] = 0ULL;
  for (int k = 0; k < NT * TOPK / 4; ++k) {
    u64 key = src[k];
    if (key > top[TOPK - 1]) {
      top[TOPK - 1] = key;
#pragma unroll
      for (int a = TOPK - 2; a >= 0; --a) {
        if (top[a + 1] > top[a]) { u64 tt = top[a]; top[a] = top[a + 1]; top[a + 1] = tt; }
      }
    }
  }
#pragma unroll
  for (int o = 0; o < TOPK; ++o) lists[tid * TOPK + o] = top[o];
  __syncthreads();
  if (q == 0) {
    for (int qq = 1; qq < 4; ++qq) {
      for (int o = 0; o < TOPK; ++o) {
        u64 key = lists[(tid + qq) * TOPK + o];
        if (key <= top[TOPK - 1]) break;   // sorted desc -> rest smaller
        top[TOPK - 1] = key;
#pragma unroll
        for (int a = TOPK - 2; a >= 0; --a) {
          if (top[a + 1] > top[a]) { u64 tt = top[a]; top[a] = top[a + 1]; top[a + 1] = tt; }
        }
      }
    }
#pragma unroll
    for (int o = 0; o < TOPK; ++o)
      topk[row * TOPK + o] = (int)(0xFFFFFFFFu - (unsigned)(top[o] & 0xFFFFFFFFu));
  }
}

// ---------------- K4: mutual-kNN lists ----------------
__global__ void k_buildV(const int* __restrict__ topk, int* __restrict__ L,
                         int* __restrict__ cnt) {
  int i = blockIdx.x * 256 + threadIdx.x;
  if (i >= N) return;
  int c = 0;
  for (int r = 0; r < TOPK; ++r) {
    int j = topk[i * TOPK + r];
    bool mut = false;
    for (int q = 0; q < TOPK; ++q) mut |= (topk[j * TOPK + q] == i);
    if (mut) L[i * TOPK + c++] = j;
  }
  cnt[i] = c;
}

// ---------------- K5: sparse W_C loss, one wave per task, sd recomputed ----------------
__global__ __launch_bounds__(256) void k_wc(const int* __restrict__ topk,
                                            const int* __restrict__ L,
                                            const int* __restrict__ cnt,
                                            const bf16* __restrict__ S,
                                            const float* __restrict__ rsq,
                                            const float* __restrict__ mean,
                                            double* __restrict__ pw) {
  int tid = threadIdx.x;
  int lane = tid & 63;
  int wv = tid >> 6;
  int task = blockIdx.x * 4 + wv;
  int i = task / TOPK_HALF, m = task % TOPK_HALF;
  int r = topk[i * TOPK + m];
  int cr = cnt[r];
  double local = 0.0;
  if (cr > 0) {
    float denom = (float)(cr > 1 ? cr : 1);
    int lval = (lane < cr) ? L[r * TOPK + lane] : -1;
    int Lr[TOPK];
#pragma unroll
    for (int a = 0; a < TOPK; ++a) Lr[a] = __shfl(lval, a, 64);
    float invmi = 1.0f / mean[i];
    float rsqi = rsq[i];
    bf16x8 vi = *(const bf16x8*)(S + (size_t)i * D + lane * 8);
    float fi[8];
#pragma unroll
    for (int k = 0; k < 8; ++k) fi[k] = (float)vi[k];
    int cj_l = 0; float mj_l = 1.0f;
    if (lane < cr) { cj_l = cnt[lval]; mj_l = mean[lval]; }
    for (int jj = 0; jj < cr; ++jj) {
      int j = Lr[jj];
      if (j == i) continue;
      int cj = __shfl(cj_l, jj, 64);
      float mj = __shfl(mj_l, jj, 64);
      bf16x8 vj = *(const bf16x8*)(S + (size_t)j * D + lane * 8);
      float dot = 0.f;
#pragma unroll
      for (int k = 0; k < 8; ++k) dot = fmaf(fi[k], (float)vj[k], dot);
#pragma unroll
      for (int off = 32; off > 0; off >>= 1) dot += __shfl_xor(dot, off, 64);
      float sq = fmaxf(rsqi + rsq[j] - 2.0f * dot, 0.0f);
      float sr_ = sqrtf(sq);
      int ljb = (lane < cj) ? L[j * TOPK + lane] : -1;
      int match = 0;
#pragma unroll
      for (int a = 0; a < TOPK; ++a) match |= ((a < cr) && (ljb == Lr[a])) ? 1 : 0;
      int vv = __popcll(__ballot(match != 0));
      float wgt = (float)vv / denom;
      float sdij = sr_ * invmi;
      float sdji = sr_ / mj;
      float Rij = fmaxf(1.0f - sdij, 0.0f); Rij *= Rij;
      float Rji = fmaxf(1.0f - sdji, 0.0f); Rji *= Rji;
      float Fij = sdij * sdij - Rij;
      float Fji = sdji * sdji - Rji;
      local += (double)(wgt * (Fij + Fji));
    }
    local *= (1.0 / 20.0);
  }
  __shared__ double red[4];
  if (lane == 0) red[wv] = local;
  __syncthreads();
  if (tid == 0) pw[blockIdx.x] = red[0] + red[1] + red[2] + red[3];
}

// ---------------- K6: final reduce ----------------
__global__ __launch_bounds__(256) void k_final(const double* __restrict__ pd,
                                               const double* __restrict__ pw,
                                               float* __restrict__ out) {
  int tid = threadIdx.x;
  double s = 0.0;
  for (int i = tid; i < NT * NT; i += 256) s += pd[i];
  for (int i = tid; i < WC_BLOCKS; i += 256) s += pw[i];
  for (int off = 32; off > 0; off >>= 1) s += __shfl_down(s, off, 64);
  __shared__ double red[4];
  if ((tid & 63) == 0) red[tid >> 6] = s;
  __syncthreads();
  if (tid == 0)
    out[0] = (float)((red[0] + red[1] + red[2] + red[3]) /
                     ((double)N * (double)(N - 1)));
}

extern "C" void kernel_launch(void* const* d_in, const int* in_sizes, int n_in,
                              void* d_out, int out_size, void* d_ws, size_t ws_size,
                              hipStream_t stream) {
  const float* s_emb = (const float*)d_in[0];
  const float* t_emb = (const float*)d_in[1];
  const int* ids = (const int*)d_in[2];
  float* out = (float*)d_out;

  char* ws = (char*)d_ws;
  size_t off = 0;
  bf16* snorm = (bf16*)(ws + off); off += (size_t)N * D * 2;        // 4 MB
  bf16* tnorm = (bf16*)(ws + off); off += (size_t)N * D * 2;        // 4 MB
  float* rsq_s = (float*)(ws + off); off += (size_t)N * 4;
  float* rsq_t = (float*)(ws + off); off += (size_t)N * 4;
  float* rowsum= (float*)(ws + off); off += (size_t)N * 4;
  float* mean  = (float*)(ws + off); off += (size_t)N * 4;
  int*   topk  = (int*)(ws + off);   off += (size_t)N * TOPK * 4;
  int*   L     = (int*)(ws + off);   off += (size_t)N * TOPK * 4;
  int*   cnt   = (int*)(ws + off);   off += (size_t)N * 4;
  off = (off + 15) & ~(size_t)15;
  u64*  cand   = (u64*)(ws + off);   off += (size_t)N * NT * TOPK * 8;   // 10.5 MB
  double* pd   = (double*)(ws + off); off += (size_t)NT * NT * 8;
  double* pw   = (double*)(ws + off); off += (size_t)WC_BLOCKS * 8;

  k_zero<<<16, 256, 0, stream>>>(rowsum);
  k_normalize<<<N, 256, 0, stream>>>(s_emb, snorm, rsq_s);
  k_normalize<<<N, 256, 0, stream>>>(t_emb, tnorm, rsq_t);
  k_sgram_rowsum<<<TRI_BLOCKS, 256, 0, stream>>>(snorm, rsq_s, rowsum);
  k_mean<<<16, 256, 0, stream>>>(rowsum, mean);
  k_fused<<<dim3(NT, NT), 256, 0, stream>>>(snorm, tnorm, rsq_s, rsq_t, mean, ids,
                                            cand, pd);
  k_merge<<<N * 4 / 256, 256, 0, stream>>>(cand, topk);
  k_buildV<<<N / 256, 256, 0, stream>>>(topk, L, cnt);
  k_wc<<<WC_BLOCKS, 256, 0, stream>>>(topk, L, cnt, snorm, rsq_s, mean, pw);
  k_final<<<1, 256, 0, stream>>>(pd, pw, out);
}